// Round 1
// baseline (828.654 us; speedup 1.0000x reference)
//
#include <hip/hip_runtime.h>
#include <hip/hip_bf16.h>

typedef __bf16 bf16_t;
typedef __attribute__((ext_vector_type(8))) __bf16 bf16x8;
typedef __attribute__((ext_vector_type(4))) __bf16 bf16x4;
typedef __attribute__((ext_vector_type(4))) float f32x4;

#define NB 4
#define NT 2048
#define NC 2048
#define NH 16
#define NKVH 4
#define ND 128
#define LDQ 3072   // qkv buffer leading dim: 2048 (q) + 512 (k) + 512 (v)

// ---------------------------------------------------------------- helpers
__device__ __forceinline__ void gld_lds16(const void* g, void* l) {
  __builtin_amdgcn_global_load_lds((__attribute__((address_space(1))) void*)g,
                                   (__attribute__((address_space(3))) void*)l,
                                   16, 0, 0);
}

// ---------------------------------------------------------------- cast fp32 -> bf16 (x4 vectorized)
__global__ __launch_bounds__(256) void cast_f32_bf16(const float* __restrict__ in,
                                                     bf16_t* __restrict__ out, int n4) {
  int i = blockIdx.x * 256 + threadIdx.x;
  if (i >= n4) return;
  float4 v = ((const float4*)in)[i];
  bf16x4 o = { (__bf16)v.x, (__bf16)v.y, (__bf16)v.z, (__bf16)v.w };
  ((bf16x4*)out)[i] = o;
}

// ---------------------------------------------------------------- rope cos/sin table (angles given as input)
__global__ __launch_bounds__(256) void rope_table(const float* __restrict__ inv_freqs,
                                                  float* __restrict__ ctab,
                                                  float* __restrict__ stab) {
  int i = blockIdx.x * 256 + threadIdx.x;   // 0 .. NT*64
  int t = i >> 6, p = i & 63;
  float ang = inv_freqs[t * ND + 2 * p];
  ctab[i] = cosf(ang);
  stab[i] = sinf(ang);
}

// ---------------------------------------------------------------- rope apply, in place on qkv (bf16), 8 elems/thread
__global__ __launch_bounds__(256) void rope_apply(bf16_t* __restrict__ qkv,
                                                  const float* __restrict__ ctab,
                                                  const float* __restrict__ stab,
                                                  int col0, int nh, float scale) {
  int idx = blockIdx.x * 256 + threadIdx.x;   // (row, h, j)
  int j = idx & 15;
  int h = (idx >> 4) % nh;
  int row = idx / (16 * nh);
  int t = row & (NT - 1);
  long off = (long)row * LDQ + col0 + h * ND + j * 8;
  bf16x8 v = *(const bf16x8*)(qkv + off);
  f32x4 c = *(const f32x4*)(ctab + t * 64 + j * 4);
  f32x4 s = *(const f32x4*)(stab + t * 64 + j * 4);
  bf16x8 r;
#pragma unroll
  for (int p = 0; p < 4; ++p) {
    float x0 = (float)v[2 * p], x1 = (float)v[2 * p + 1];
    r[2 * p]     = (__bf16)((x0 * c[p] - x1 * s[p]) * scale);
    r[2 * p + 1] = (__bf16)((x1 * c[p] + x0 * s[p]) * scale);
  }
  *(bf16x8*)(qkv + off) = r;
}

// ---------------------------------------------------------------- GEMM: C[M,N] = A[M,K] * Bt[N,K]^T (+bias)
// m97 structure: 128x128 tile, BK=32, 4 waves, 4x4 acc/wave, global_load_lds w16, 2-barrier loop.
template <bool OUT_BF16>
__global__ __launch_bounds__(256) void gemm_bt(const bf16_t* __restrict__ A,
                                               const bf16_t* __restrict__ Bt,
                                               void* __restrict__ Cout,
                                               const float* __restrict__ bias,
                                               int M, int N, int K) {
  __shared__ __align__(16) bf16_t As[128 * 32];
  __shared__ __align__(16) bf16_t Bs[128 * 32];
  const int tid = threadIdx.x;
  const int wid = tid >> 6, lane = tid & 63;
  const int wm = wid >> 1, wn = wid & 1;
  const long am0 = (long)blockIdx.x * 128;
  const long bn0 = (long)blockIdx.y * 128;

  f32x4 acc[4][4] = {};

  // staging: wave stages rows [wid*32, wid*32+32) of each tile, 2 insts x 16 rows
  const int srow = wid * 32 + (lane >> 2);
  const int skoff = (lane & 3) * 8;
  const bf16_t* ag0 = A + (am0 + srow) * K + skoff;
  const bf16_t* ag1 = A + (am0 + srow + 16) * K + skoff;
  const bf16_t* bg0 = Bt + (bn0 + srow) * K + skoff;
  const bf16_t* bg1 = Bt + (bn0 + srow + 16) * K + skoff;
  bf16_t* al0 = As + (wid * 32) * 32;
  bf16_t* al1 = As + (wid * 32 + 16) * 32;
  bf16_t* bl0 = Bs + (wid * 32) * 32;
  bf16_t* bl1 = Bs + (wid * 32 + 16) * 32;

  const int fr = lane & 15;
  const int fk = (lane >> 4) * 8;
  const bf16_t* afrag = As + (wm * 64 + fr) * 32 + fk;
  const bf16_t* bfrag = Bs + (wn * 64 + fr) * 32 + fk;

  for (int k0 = 0; k0 < K; k0 += 32) {
    gld_lds16(ag0 + k0, al0);
    gld_lds16(ag1 + k0, al1);
    gld_lds16(bg0 + k0, bl0);
    gld_lds16(bg1 + k0, bl1);
    __syncthreads();
    bf16x8 a[4], b[4];
#pragma unroll
    for (int i = 0; i < 4; ++i) a[i] = *(const bf16x8*)(afrag + i * 16 * 32);
#pragma unroll
    for (int i = 0; i < 4; ++i) b[i] = *(const bf16x8*)(bfrag + i * 16 * 32);
#pragma unroll
    for (int mi = 0; mi < 4; ++mi)
#pragma unroll
      for (int ni = 0; ni < 4; ++ni)
        acc[mi][ni] = __builtin_amdgcn_mfma_f32_16x16x32_bf16(a[mi], b[ni], acc[mi][ni], 0, 0, 0);
    __syncthreads();
  }

  const int orow = wm * 64 + ((lane >> 4) << 2);
  const int ocol = wn * 64 + (lane & 15);
#pragma unroll
  for (int mi = 0; mi < 4; ++mi)
#pragma unroll
    for (int ni = 0; ni < 4; ++ni) {
      long col = bn0 + ocol + ni * 16;
#pragma unroll
      for (int r = 0; r < 4; ++r) {
        long row = am0 + orow + mi * 16 + r;
        float vv = acc[mi][ni][r];
        if (OUT_BF16) ((bf16_t*)Cout)[row * N + col] = (__bf16)vv;
        else          ((float*)Cout)[row * N + col] = vv + bias[col];
      }
    }
}

// ---------------------------------------------------------------- flash attention (causal, GQA)
// 4 waves x 16 q-rows (QBLK=64), KVBLK=64, 16x16x32 bf16 MFMA.
// LDS tiles XOR-swizzled: byte_in_row ^= (row&7)<<4  (K staged via pre-swizzled global src).
__global__ __launch_bounds__(256) void attn_fwd(const bf16_t* __restrict__ qkv,
                                                bf16_t* __restrict__ y) {
  __shared__ __align__(16) bf16_t Kt[64 * 128];   // [kv][d], swizzled rows of 256B
  __shared__ __align__(16) bf16_t Vt[128 * 64];   // [d][kv], swizzled rows of 128B
  __shared__ __align__(16) bf16_t Pb[4][16 * 64]; // per-wave P, swizzled rows of 128B
  char* KtB = (char*)Kt;
  char* VtB = (char*)Vt;

  const int tid = threadIdx.x, wid = tid >> 6, lane = tid & 63;
  const int bh = blockIdx.y;
  const int b = bh >> 4, h = bh & 15, kvh = h >> 2;
  const int q0 = ((int)gridDim.x - 1 - (int)blockIdx.x) * 64;  // long blocks first
  const long rowbase = (long)b * NT;
  const int fr = lane & 15, fg = lane >> 4;
  char* PbB = (char*)Pb[wid];

  // Q fragments (registers, scale pre-folded in rope)
  bf16x8 qf[4];
  {
    const bf16_t* qp = qkv + (rowbase + q0 + wid * 16 + fr) * (long)LDQ + h * ND + fg * 8;
#pragma unroll
    for (int ks = 0; ks < 4; ++ks) qf[ks] = *(const bf16x8*)(qp + ks * 32);
  }

  f32x4 o[8] = {};
  float m_st[4], l_st[4];
#pragma unroll
  for (int r = 0; r < 4; ++r) { m_st[r] = -3e38f; l_st[r] = 0.f; }

  // V staging assignment: thread -> kv row tid/4, d-chunk (tid%4)*32
  const int vkvl = tid >> 2;
  const int vdc = (tid & 3) * 32;
  const bf16_t* vg = qkv + (rowbase + vkvl) * (long)LDQ + 2560 + kvh * ND + vdc;

  const int ntiles = q0 / 64 + 1;
  for (int t = 0; t < ntiles; ++t) {
    const int kv0 = t * 64;
    // ---- stage K via global_load_lds, source pre-swizzled
#pragma unroll
    for (int i = 0; i < 4; ++i) {
      int kvl = wid * 16 + i * 4 + fg;                       // row this lane covers
      int dbyte = ((lane & 15) * 16) ^ ((kvl & 7) << 4);     // inverse swizzle on source
      const bf16_t* g = qkv + (rowbase + kv0 + kvl) * (long)LDQ + NC + kvh * ND + (dbyte >> 1);
      gld_lds16(g, Kt + (wid * 16 + i * 4) * 128);
    }
    // ---- stage V transposed (scalar swizzled writes)
    {
      const bf16_t* vp = vg + (long)kv0 * LDQ;
      bf16x8 vv[4];
#pragma unroll
      for (int j = 0; j < 4; ++j) vv[j] = *(const bf16x8*)(vp + j * 8);
#pragma unroll
      for (int j = 0; j < 4; ++j)
#pragma unroll
        for (int e = 0; e < 8; ++e) {
          int d = vdc + j * 8 + e;
          int byte = d * 128 + ((vkvl * 2) ^ ((d & 7) << 4));
          *(bf16_t*)(VtB + byte) = vv[j][e];
        }
    }
    __syncthreads();

    // ---- S = Q K^T
    f32x4 s[4] = {};
#pragma unroll
    for (int ks = 0; ks < 4; ++ks) {
#pragma unroll
      for (int ni = 0; ni < 4; ++ni) {
        bf16x8 kb = *(const bf16x8*)(KtB + (ni * 16 + fr) * 256 +
                                     (((ks * 64 + fg * 16) ^ ((fr & 7) << 4))));
        s[ni] = __builtin_amdgcn_mfma_f32_16x16x32_bf16(qf[ks], kb, s[ni], 0, 0, 0);
      }
    }
    // ---- causal mask (diagonal tile only)
    if (kv0 == q0) {
#pragma unroll
      for (int ni = 0; ni < 4; ++ni) {
        int j = kv0 + ni * 16 + fr;
#pragma unroll
        for (int r = 0; r < 4; ++r) {
          int i_ = q0 + wid * 16 + fg * 4 + r;
          if (j > i_) s[ni][r] = -3e30f;
        }
      }
    }
    // ---- online softmax (rows live in 16-lane groups; butterfly over lanes 1,2,4,8)
    float alpha[4];
#pragma unroll
    for (int r = 0; r < 4; ++r) {
      float rm = fmaxf(fmaxf(s[0][r], s[1][r]), fmaxf(s[2][r], s[3][r]));
      rm = fmaxf(rm, __shfl_xor(rm, 1));
      rm = fmaxf(rm, __shfl_xor(rm, 2));
      rm = fmaxf(rm, __shfl_xor(rm, 4));
      rm = fmaxf(rm, __shfl_xor(rm, 8));
      float mn = fmaxf(m_st[r], rm);
      alpha[r] = __expf(m_st[r] - mn);
      m_st[r] = mn;
    }
#pragma unroll
    for (int ni = 0; ni < 4; ++ni)
#pragma unroll
      for (int r = 0; r < 4; ++r)
        s[ni][r] = __expf(s[ni][r] - m_st[r]);
#pragma unroll
    for (int r = 0; r < 4; ++r) {
      float t2 = s[0][r] + s[1][r] + s[2][r] + s[3][r];
      t2 += __shfl_xor(t2, 1);
      t2 += __shfl_xor(t2, 2);
      t2 += __shfl_xor(t2, 4);
      t2 += __shfl_xor(t2, 8);
      l_st[r] = l_st[r] * alpha[r] + t2;
    }
    // ---- rescale O
#pragma unroll
    for (int n = 0; n < 8; ++n)
#pragma unroll
      for (int r = 0; r < 4; ++r) o[n][r] *= alpha[r];
    // ---- P -> LDS (bf16, swizzled), then A-frags for PV
#pragma unroll
    for (int ni = 0; ni < 4; ++ni)
#pragma unroll
      for (int r = 0; r < 4; ++r) {
        int m = fg * 4 + r;
        int byte = m * 128 + (((ni * 32 + fr * 2)) ^ ((m & 7) << 4));
        *(bf16_t*)(PbB + byte) = (__bf16)s[ni][r];
      }
    bf16x8 pa[2];
#pragma unroll
    for (int ks = 0; ks < 2; ++ks)
      pa[ks] = *(const bf16x8*)(PbB + fr * 128 + (((ks * 64 + fg * 16)) ^ ((fr & 7) << 4)));
    // ---- O += P V
#pragma unroll
    for (int ks = 0; ks < 2; ++ks)
#pragma unroll
      for (int n = 0; n < 8; ++n) {
        bf16x8 vb = *(const bf16x8*)(VtB + (n * 16 + fr) * 128 +
                                     (((ks * 64 + fg * 16) ^ ((fr & 7) << 4))));
        o[n] = __builtin_amdgcn_mfma_f32_16x16x32_bf16(pa[ks], vb, o[n], 0, 0, 0);
      }
    __syncthreads();
  }

  // ---- epilogue: O /= l, write y[b,t, h*128+d] bf16
#pragma unroll
  for (int r = 0; r < 4; ++r) {
    float rinv = 1.0f / l_st[r];
    long row = rowbase + q0 + wid * 16 + fg * 4 + r;
#pragma unroll
    for (int n = 0; n < 8; ++n)
      y[row * NC + h * ND + n * 16 + fr] = (__bf16)(o[n][r] * rinv);
  }
}

// ---------------------------------------------------------------- launch
extern "C" void kernel_launch(void* const* d_in, const int* in_sizes, int n_in,
                              void* d_out, int out_size, void* d_ws, size_t ws_size,
                              hipStream_t stream) {
  const float* x  = (const float*)d_in[0];
  // d_in[1] = start_pos (0), d_in[3] = mask — causal handled analytically
  const float* iv = (const float*)d_in[2];
  const float* Wq = (const float*)d_in[4];
  const float* Wk = (const float*)d_in[5];
  const float* Wv = (const float*)d_in[6];
  const float* Wo = (const float*)d_in[7];
  const float* bo = (const float*)d_in[8];
  float* out = (float*)d_out;

  char* ws = (char*)d_ws;
  size_t off = 0;
  auto alloc = [&](size_t bytes) -> void* {
    void* p = ws + off;
    off += (bytes + 255) & ~(size_t)255;
    return p;
  };
  bf16_t* xb   = (bf16_t*)alloc((size_t)NB * NT * NC * 2);        // 33.5 MB
  bf16_t* Wcat = (bf16_t*)alloc((size_t)3072 * 2048 * 2);         // 12.6 MB
  bf16_t* Wob  = (bf16_t*)alloc((size_t)2048 * 2048 * 2);         //  8.4 MB
  bf16_t* qkv  = (bf16_t*)alloc((size_t)NB * NT * LDQ * 2);       // 50.3 MB
  bf16_t* yb   = (bf16_t*)alloc((size_t)NB * NT * NC * 2);        // 33.5 MB
  float*  ctab = (float*)alloc((size_t)NT * 64 * 4);
  float*  stab = (float*)alloc((size_t)NT * 64 * 4);

  // casts (bf16)
  cast_f32_bf16<<<16384, 256, 0, stream>>>(x, xb, 4194304);
  cast_f32_bf16<<<4096, 256, 0, stream>>>(Wq, Wcat, 1048576);
  cast_f32_bf16<<<1024, 256, 0, stream>>>(Wk, Wcat + (size_t)2048 * 2048, 262144);
  cast_f32_bf16<<<1024, 256, 0, stream>>>(Wv, Wcat + (size_t)2560 * 2048, 262144);
  cast_f32_bf16<<<4096, 256, 0, stream>>>(Wo, Wob, 1048576);
  rope_table<<<512, 256, 0, stream>>>(iv, ctab, stab);

  // fused QKV projection: [8192,2048] x [3072,2048]^T -> qkv bf16
  gemm_bt<true><<<dim3(64, 24), 256, 0, stream>>>(xb, Wcat, qkv, nullptr, 8192, 3072, 2048);

  // RoPE in place (q gets 1/sqrt(D) folded in)
  rope_apply<<<8192, 256, 0, stream>>>(qkv, ctab, stab, 0, NH, 0.08838834764831843f);
  rope_apply<<<2048, 256, 0, stream>>>(qkv, ctab, stab, NC, NKVH, 1.0f);

  // causal GQA flash attention -> yb bf16
  attn_fwd<<<dim3(32, 64), 256, 0, stream>>>(qkv, yb);

  // output projection + bias -> fp32 out
  gemm_bt<false><<<dim3(64, 16), 256, 0, stream>>>(yb, Wob, out, bo, 8192, 2048, 2048);
}

// Round 2
// 667.347 us; speedup vs baseline: 1.2417x; 1.2417x over previous
//
#include <hip/hip_runtime.h>
#include <hip/hip_bf16.h>

typedef __bf16 bf16_t;
typedef __attribute__((ext_vector_type(8))) __bf16 bf16x8;
typedef __attribute__((ext_vector_type(4))) __bf16 bf16x4;
typedef __attribute__((ext_vector_type(4))) float f32x4;

#define NB 4
#define NT 2048
#define NC 2048
#define NH 16
#define NKVH 4
#define ND 128
#define LDQ 2560   // qkv buffer leading dim: 2048 (q) + 512 (k); V lives transposed elsewhere

// ---------------------------------------------------------------- helpers
__device__ __forceinline__ void gld_lds16(const void* g, void* l) {
  __builtin_amdgcn_global_load_lds((__attribute__((address_space(1))) void*)g,
                                   (__attribute__((address_space(3))) void*)l,
                                   16, 0, 0);
}

// ---------------------------------------------------------------- cast fp32 -> bf16 (x4 vectorized)
__global__ __launch_bounds__(256) void cast_f32_bf16(const float* __restrict__ in,
                                                     bf16_t* __restrict__ out, int n4) {
  int i = blockIdx.x * 256 + threadIdx.x;
  if (i >= n4) return;
  float4 v = ((const float4*)in)[i];
  bf16x4 o = { (__bf16)v.x, (__bf16)v.y, (__bf16)v.z, (__bf16)v.w };
  ((bf16x4*)out)[i] = o;
}

// ---------------------------------------------------------------- rope cos/sin table (angles given as input)
__global__ __launch_bounds__(256) void rope_table(const float* __restrict__ inv_freqs,
                                                  float* __restrict__ ctab,
                                                  float* __restrict__ stab) {
  int i = blockIdx.x * 256 + threadIdx.x;   // 0 .. NT*64
  int t = i >> 6, p = i & 63;
  float ang = inv_freqs[t * ND + 2 * p];
  ctab[i] = cosf(ang);
  stab[i] = sinf(ang);
}

// ---------------------------------------------------------------- rope apply, in place on qkv (bf16), 8 elems/thread
__global__ __launch_bounds__(256) void rope_apply(bf16_t* __restrict__ qkv,
                                                  const float* __restrict__ ctab,
                                                  const float* __restrict__ stab,
                                                  int col0, int nh, float scale) {
  int idx = blockIdx.x * 256 + threadIdx.x;   // (row, h, j)
  int j = idx & 15;
  int h = (idx >> 4) % nh;
  int row = idx / (16 * nh);
  int t = row & (NT - 1);
  long off = (long)row * LDQ + col0 + h * ND + j * 8;
  bf16x8 v = *(const bf16x8*)(qkv + off);
  f32x4 c = *(const f32x4*)(ctab + t * 64 + j * 4);
  f32x4 s = *(const f32x4*)(stab + t * 64 + j * 4);
  bf16x8 r;
#pragma unroll
  for (int p = 0; p < 4; ++p) {
    float x0 = (float)v[2 * p], x1 = (float)v[2 * p + 1];
    r[2 * p]     = (__bf16)((x0 * c[p] - x1 * s[p]) * scale);
    r[2 * p + 1] = (__bf16)((x1 * c[p] + x0 * s[p]) * scale);
  }
  *(bf16x8*)(qkv + off) = r;
}

// ---------------------------------------------------------------- GEMM: C[M,N] = A[M,K] * Bt[N,K]^T (+bias)
// m97 structure: 128x128 tile, BK=32, 4 waves, 4x4 acc/wave, global_load_lds w16, 2-barrier loop.
template <bool OUT_BF16>
__global__ __launch_bounds__(256) void gemm_bt(const bf16_t* __restrict__ A,
                                               const bf16_t* __restrict__ Bt,
                                               void* __restrict__ Cout,
                                               const float* __restrict__ bias,
                                               int M, int N, int K) {
  __shared__ __align__(16) bf16_t As[128 * 32];
  __shared__ __align__(16) bf16_t Bs[128 * 32];
  const int tid = threadIdx.x;
  const int wid = tid >> 6, lane = tid & 63;
  const int wm = wid >> 1, wn = wid & 1;
  const long am0 = (long)blockIdx.x * 128;
  const long bn0 = (long)blockIdx.y * 128;

  f32x4 acc[4][4] = {};

  const int srow = wid * 32 + (lane >> 2);
  const int skoff = (lane & 3) * 8;
  const bf16_t* ag0 = A + (am0 + srow) * K + skoff;
  const bf16_t* ag1 = A + (am0 + srow + 16) * K + skoff;
  const bf16_t* bg0 = Bt + (bn0 + srow) * K + skoff;
  const bf16_t* bg1 = Bt + (bn0 + srow + 16) * K + skoff;
  bf16_t* al0 = As + (wid * 32) * 32;
  bf16_t* al1 = As + (wid * 32 + 16) * 32;
  bf16_t* bl0 = Bs + (wid * 32) * 32;
  bf16_t* bl1 = Bs + (wid * 32 + 16) * 32;

  const int fr = lane & 15;
  const int fk = (lane >> 4) * 8;
  const bf16_t* afrag = As + (wm * 64 + fr) * 32 + fk;
  const bf16_t* bfrag = Bs + (wn * 64 + fr) * 32 + fk;

  for (int k0 = 0; k0 < K; k0 += 32) {
    gld_lds16(ag0 + k0, al0);
    gld_lds16(ag1 + k0, al1);
    gld_lds16(bg0 + k0, bl0);
    gld_lds16(bg1 + k0, bl1);
    __syncthreads();
    bf16x8 a[4], b[4];
#pragma unroll
    for (int i = 0; i < 4; ++i) a[i] = *(const bf16x8*)(afrag + i * 16 * 32);
#pragma unroll
    for (int i = 0; i < 4; ++i) b[i] = *(const bf16x8*)(bfrag + i * 16 * 32);
#pragma unroll
    for (int mi = 0; mi < 4; ++mi)
#pragma unroll
      for (int ni = 0; ni < 4; ++ni)
        acc[mi][ni] = __builtin_amdgcn_mfma_f32_16x16x32_bf16(a[mi], b[ni], acc[mi][ni], 0, 0, 0);
    __syncthreads();
  }

  const int orow = wm * 64 + ((lane >> 4) << 2);
  const int ocol = wn * 64 + (lane & 15);
#pragma unroll
  for (int mi = 0; mi < 4; ++mi)
#pragma unroll
    for (int ni = 0; ni < 4; ++ni) {
      long col = bn0 + ocol + ni * 16;
#pragma unroll
      for (int r = 0; r < 4; ++r) {
        long row = am0 + orow + mi * 16 + r;
        float vv = acc[mi][ni][r];
        if (OUT_BF16) ((bf16_t*)Cout)[row * N + col] = (__bf16)vv;
        else          ((float*)Cout)[row * N + col] = vv + bias[col];
      }
    }
}

// ---------------------------------------------------------------- flash attention (causal, GQA)
// 4 waves x 32 q-rows (QBLK=128), KVBLK=64, double-buffered K/V via global_load_lds,
// 2-phase prefetch, q-tile pairing (bx, 15-bx) for uniform causal cost.
// LDS rows XOR-swizzled: byte_in_row ^= (row&7)<<4, staged via pre-swizzled global src.
__global__ __launch_bounds__(256) void attn_fwd(const bf16_t* __restrict__ qkv,
                                                const bf16_t* __restrict__ vt,
                                                bf16_t* __restrict__ y) {
  __shared__ __align__(16) bf16_t Kt[2][64 * 128];   // [kv][d] rows of 256B, swizzled
  __shared__ __align__(16) bf16_t Vt[2][128 * 64];   // [d][kv] rows of 128B, swizzled
  __shared__ __align__(16) bf16_t Pb[4][32 * 64];    // per-wave P, rows of 128B, swizzled

  const int tid = threadIdx.x, wid = tid >> 6, lane = tid & 63;
  const int fr = lane & 15, fg = lane >> 4;
  const int bh = blockIdx.y;
  const int b = bh >> 4, h = bh & 15, kvh = h >> 2;
  const int bx = blockIdx.x;               // 0..7; handles q-tiles bx and 15-bx
  const long rowbase = (long)b * NT;
  char* PbB = (char*)Pb[wid];

  // per-lane staging sources (kv0 added per tile)
  const bf16_t* ksrc[4];
  const bf16_t* vsrc[4];
#pragma unroll
  for (int i = 0; i < 4; ++i) {
    int kvl = wid * 16 + i * 4 + fg;
    int dbyte = ((lane & 15) * 16) ^ ((kvl & 7) << 4);
    ksrc[i] = qkv + (rowbase + kvl) * (long)LDQ + NC + kvh * ND + (dbyte >> 1);
    int d = wid * 32 + i * 8 + (lane >> 3);
    int kvbyte = ((lane & 7) * 16) ^ ((d & 7) << 4);
    vsrc[i] = vt + (long)(kvh * ND + d) * (NB * NT) + rowbase + (kvbyte >> 1);
  }

  auto STAGE = [&](int buf, int kv0) {
#pragma unroll
    for (int i = 0; i < 4; ++i)
      gld_lds16(ksrc[i] + (long)kv0 * LDQ, &Kt[buf][(wid * 16 + i * 4) * 128]);
#pragma unroll
    for (int i = 0; i < 4; ++i)
      gld_lds16(vsrc[i] + kv0, &Vt[buf][(wid * 32 + i * 8) * 64]);
  };

  int cur = 0;
#pragma unroll 1
  for (int phase = 0; phase < 2; ++phase) {
    const int qt = phase ? (15 - bx) : bx;
    const int q0 = qt * 128;
    const int ntiles = 2 * qt + 2;

    // Q fragments (scale folded in rope)
    bf16x8 qf[2][4];
#pragma unroll
    for (int mi = 0; mi < 2; ++mi) {
      const bf16_t* qp = qkv + (rowbase + q0 + wid * 32 + mi * 16 + fr) * (long)LDQ + h * ND + fg * 8;
#pragma unroll
      for (int ks = 0; ks < 4; ++ks) qf[mi][ks] = *(const bf16x8*)(qp + ks * 32);
    }

    f32x4 o[2][8] = {};
    float m_st[2][4], l_st[2][4];
#pragma unroll
    for (int mi = 0; mi < 2; ++mi)
#pragma unroll
      for (int r = 0; r < 4; ++r) { m_st[mi][r] = -3e38f; l_st[mi][r] = 0.f; }

    STAGE(cur, 0);
    __syncthreads();

#pragma unroll 1
    for (int t = 0; t < ntiles; ++t) {
      const int kv0 = t * 64;
      if (t + 1 < ntiles) STAGE(cur ^ 1, kv0 + 64);

      const char* KtB = (const char*)Kt[cur];
      const char* VtB = (const char*)Vt[cur];

      // ---- S = Q K^T  (rows=q, cols=kv)
      f32x4 s[2][4] = {};
#pragma unroll
      for (int ks = 0; ks < 4; ++ks)
#pragma unroll
        for (int ni = 0; ni < 4; ++ni) {
          bf16x8 kb = *(const bf16x8*)(KtB + (ni * 16 + fr) * 256 +
                                       ((ks * 64 + fg * 16) ^ ((fr & 7) << 4)));
          s[0][ni] = __builtin_amdgcn_mfma_f32_16x16x32_bf16(qf[0][ks], kb, s[0][ni], 0, 0, 0);
          s[1][ni] = __builtin_amdgcn_mfma_f32_16x16x32_bf16(qf[1][ks], kb, s[1][ni], 0, 0, 0);
        }

      // ---- causal mask (last two tiles only)
      if (t >= 2 * qt) {
#pragma unroll
        for (int mi = 0; mi < 2; ++mi)
#pragma unroll
          for (int ni = 0; ni < 4; ++ni) {
            int j = kv0 + ni * 16 + fr;
#pragma unroll
            for (int r = 0; r < 4; ++r) {
              int i_ = q0 + wid * 32 + mi * 16 + fg * 4 + r;
              if (j > i_) s[mi][ni][r] = -3e30f;
            }
          }
      }

      // ---- online softmax (rows in 16-lane groups)
      float alpha[2][4];
#pragma unroll
      for (int mi = 0; mi < 2; ++mi)
#pragma unroll
        for (int r = 0; r < 4; ++r) {
          float rm = fmaxf(fmaxf(s[mi][0][r], s[mi][1][r]), fmaxf(s[mi][2][r], s[mi][3][r]));
          rm = fmaxf(rm, __shfl_xor(rm, 1));
          rm = fmaxf(rm, __shfl_xor(rm, 2));
          rm = fmaxf(rm, __shfl_xor(rm, 4));
          rm = fmaxf(rm, __shfl_xor(rm, 8));
          float mn = fmaxf(m_st[mi][r], rm);
          alpha[mi][r] = __expf(m_st[mi][r] - mn);
          m_st[mi][r] = mn;
        }
#pragma unroll
      for (int mi = 0; mi < 2; ++mi)
#pragma unroll
        for (int ni = 0; ni < 4; ++ni)
#pragma unroll
          for (int r = 0; r < 4; ++r)
            s[mi][ni][r] = __expf(s[mi][ni][r] - m_st[mi][r]);
#pragma unroll
      for (int mi = 0; mi < 2; ++mi)
#pragma unroll
        for (int r = 0; r < 4; ++r) {
          float t2 = s[mi][0][r] + s[mi][1][r] + s[mi][2][r] + s[mi][3][r];
          t2 += __shfl_xor(t2, 1);
          t2 += __shfl_xor(t2, 2);
          t2 += __shfl_xor(t2, 4);
          t2 += __shfl_xor(t2, 8);
          l_st[mi][r] = l_st[mi][r] * alpha[mi][r] + t2;
        }
      // ---- rescale O
#pragma unroll
      for (int mi = 0; mi < 2; ++mi)
#pragma unroll
        for (int n = 0; n < 8; ++n)
#pragma unroll
          for (int r = 0; r < 4; ++r) o[mi][n][r] *= alpha[mi][r];

      // ---- P -> LDS (bf16, swizzled rows of 128B)
#pragma unroll
      for (int mi = 0; mi < 2; ++mi)
#pragma unroll
        for (int ni = 0; ni < 4; ++ni)
#pragma unroll
          for (int r = 0; r < 4; ++r) {
            int m = mi * 16 + fg * 4 + r;
            int byte = m * 128 + ((ni * 32 + fr * 2) ^ ((m & 7) << 4));
            *(bf16_t*)(PbB + byte) = (__bf16)s[mi][ni][r];
          }
      bf16x8 pa[2][2];
#pragma unroll
      for (int mi = 0; mi < 2; ++mi)
#pragma unroll
        for (int ks = 0; ks < 2; ++ks) {
          int m = mi * 16 + fr;
          pa[mi][ks] = *(const bf16x8*)(PbB + m * 128 + ((ks * 64 + fg * 16) ^ ((m & 7) << 4)));
        }
      // ---- O += P V
#pragma unroll
      for (int ks = 0; ks < 2; ++ks)
#pragma unroll
        for (int n = 0; n < 8; ++n) {
          bf16x8 vb = *(const bf16x8*)(VtB + (n * 16 + fr) * 128 +
                                       ((ks * 64 + fg * 16) ^ ((fr & 7) << 4)));
          o[0][n] = __builtin_amdgcn_mfma_f32_16x16x32_bf16(pa[0][ks], vb, o[0][n], 0, 0, 0);
          o[1][n] = __builtin_amdgcn_mfma_f32_16x16x32_bf16(pa[1][ks], vb, o[1][n], 0, 0, 0);
        }
      __syncthreads();
      cur ^= 1;
    }

    // ---- epilogue: O /= l
#pragma unroll
    for (int mi = 0; mi < 2; ++mi)
#pragma unroll
      for (int r = 0; r < 4; ++r) {
        float rinv = 1.0f / l_st[mi][r];
        long row = rowbase + q0 + wid * 32 + mi * 16 + fg * 4 + r;
#pragma unroll
        for (int n = 0; n < 8; ++n)
          y[row * NC + h * ND + n * 16 + fr] = (__bf16)(o[mi][n][r] * rinv);
      }
  }
}

// ---------------------------------------------------------------- launch
extern "C" void kernel_launch(void* const* d_in, const int* in_sizes, int n_in,
                              void* d_out, int out_size, void* d_ws, size_t ws_size,
                              hipStream_t stream) {
  const float* x  = (const float*)d_in[0];
  const float* iv = (const float*)d_in[2];
  const float* Wq = (const float*)d_in[4];
  const float* Wk = (const float*)d_in[5];
  const float* Wv = (const float*)d_in[6];
  const float* Wo = (const float*)d_in[7];
  const float* bo = (const float*)d_in[8];
  float* out = (float*)d_out;

  char* ws = (char*)d_ws;
  size_t off = 0;
  auto alloc = [&](size_t bytes) -> void* {
    void* p = ws + off;
    off += (bytes + 255) & ~(size_t)255;
    return p;
  };
  bf16_t* xb   = (bf16_t*)alloc((size_t)NB * NT * NC * 2);        // 33.5 MB
  bf16_t* Wcat = (bf16_t*)alloc((size_t)2560 * 2048 * 2);         // 10.5 MB (Wq|Wk)
  bf16_t* Wvb  = (bf16_t*)alloc((size_t)512 * 2048 * 2);          //  2.1 MB
  bf16_t* Wob  = (bf16_t*)alloc((size_t)2048 * 2048 * 2);         //  8.4 MB
  bf16_t* qkv  = (bf16_t*)alloc((size_t)NB * NT * LDQ * 2);       // 41.9 MB
  bf16_t* vtb  = (bf16_t*)alloc((size_t)512 * NB * NT * 2);       //  8.4 MB (V^T: [kvh*128+d][b*t])
  bf16_t* yb   = (bf16_t*)alloc((size_t)NB * NT * NC * 2);        // 33.5 MB
  float*  ctab = (float*)alloc((size_t)NT * 64 * 4);
  float*  stab = (float*)alloc((size_t)NT * 64 * 4);

  // casts (bf16)
  cast_f32_bf16<<<16384, 256, 0, stream>>>(x, xb, 4194304);
  cast_f32_bf16<<<4096, 256, 0, stream>>>(Wq, Wcat, 1048576);
  cast_f32_bf16<<<1024, 256, 0, stream>>>(Wk, Wcat + (size_t)2048 * 2048, 262144);
  cast_f32_bf16<<<1024, 256, 0, stream>>>(Wv, Wvb, 262144);
  cast_f32_bf16<<<4096, 256, 0, stream>>>(Wo, Wob, 1048576);
  rope_table<<<512, 256, 0, stream>>>(iv, ctab, stab);

  // fused Q|K projection: [8192,2048] x [2560,2048]^T -> qkv bf16
  gemm_bt<true><<<dim3(64, 20), 256, 0, stream>>>(xb, Wcat, qkv, nullptr, 8192, 2560, 2048);
  // V^T projection: [512,2048] x [8192,2048]^T -> vtb[d][b*t]
  gemm_bt<true><<<dim3(4, 64), 256, 0, stream>>>(Wvb, xb, vtb, nullptr, 512, 8192, 2048);

  // RoPE in place (q gets 1/sqrt(D) folded in)
  rope_apply<<<8192, 256, 0, stream>>>(qkv, ctab, stab, 0, NH, 0.08838834764831843f);
  rope_apply<<<2048, 256, 0, stream>>>(qkv, ctab, stab, NC, NKVH, 1.0f);

  // causal GQA flash attention -> yb bf16
  attn_fwd<<<dim3(8, 64), 256, 0, stream>>>(qkv, vtb, yb);

  // output projection + bias -> fp32 out
  gemm_bt<false><<<dim3(64, 16), 256, 0, stream>>>(yb, Wob, out, bo, 8192, 2048, 2048);
}

// Round 6
// 635.267 us; speedup vs baseline: 1.3044x; 1.0505x over previous
//
#include <hip/hip_runtime.h>
#include <hip/hip_bf16.h>

typedef __bf16 bf16_t;
typedef __attribute__((ext_vector_type(8))) __bf16 bf16x8;
typedef __attribute__((ext_vector_type(4))) __bf16 bf16x4;
typedef __attribute__((ext_vector_type(4))) float f32x4;

#define NB 4
#define NT 2048
#define NC 2048
#define NH 16
#define NKVH 4
#define ND 128
#define LDQ 2560   // qkv buffer leading dim: 2048 (q) + 512 (k); V lives transposed elsewhere

// ---------------------------------------------------------------- helpers
__device__ __forceinline__ void gld_lds16(const void* g, void* l) {
  __builtin_amdgcn_global_load_lds((__attribute__((address_space(1))) void*)g,
                                   (__attribute__((address_space(3))) void*)l,
                                   16, 0, 0);
}

// ---------------------------------------------------------------- cast fp32 -> bf16 (x4 vectorized)
__global__ __launch_bounds__(256) void cast_f32_bf16(const float* __restrict__ in,
                                                     bf16_t* __restrict__ out, int n4) {
  int i = blockIdx.x * 256 + threadIdx.x;
  if (i >= n4) return;
  float4 v = ((const float4*)in)[i];
  bf16x4 o = { (__bf16)v.x, (__bf16)v.y, (__bf16)v.z, (__bf16)v.w };
  ((bf16x4*)out)[i] = o;
}

// ---------------------------------------------------------------- rope cos/sin table
__global__ __launch_bounds__(256) void rope_table(const float* __restrict__ inv_freqs,
                                                  float* __restrict__ ctab,
                                                  float* __restrict__ stab) {
  int i = blockIdx.x * 256 + threadIdx.x;   // 0 .. NT*64
  int t = i >> 6, p = i & 63;
  float ang = inv_freqs[t * ND + 2 * p];
  ctab[i] = cosf(ang);
  stab[i] = sinf(ang);
}

// ---------------------------------------------------------------- rope apply, in place on qkv
__global__ __launch_bounds__(256) void rope_apply(bf16_t* __restrict__ qkv,
                                                  const float* __restrict__ ctab,
                                                  const float* __restrict__ stab,
                                                  int col0, int nh, float scale) {
  int idx = blockIdx.x * 256 + threadIdx.x;   // (row, h, j)
  int j = idx & 15;
  int h = (idx >> 4) % nh;
  int row = idx / (16 * nh);
  int t = row & (NT - 1);
  long off = (long)row * LDQ + col0 + h * ND + j * 8;
  bf16x8 v = *(const bf16x8*)(qkv + off);
  f32x4 c = *(const f32x4*)(ctab + t * 64 + j * 4);
  f32x4 s = *(const f32x4*)(stab + t * 64 + j * 4);
  bf16x8 r;
#pragma unroll
  for (int p = 0; p < 4; ++p) {
    float x0 = (float)v[2 * p], x1 = (float)v[2 * p + 1];
    r[2 * p]     = (__bf16)((x0 * c[p] - x1 * s[p]) * scale);
    r[2 * p + 1] = (__bf16)((x1 * c[p] + x0 * s[p]) * scale);
  }
  *(bf16x8*)(qkv + off) = r;
}

// ---------------------------------------------------------------- GEMM (m97 128^2) kept for V^T (skinny M)
template <bool OUT_BF16>
__global__ __launch_bounds__(256) void gemm_bt(const bf16_t* __restrict__ A,
                                               const bf16_t* __restrict__ Bt,
                                               void* __restrict__ Cout,
                                               const float* __restrict__ bias,
                                               int M, int N, int K) {
  __shared__ __align__(16) bf16_t As[128 * 32];
  __shared__ __align__(16) bf16_t Bs[128 * 32];
  const int tid = threadIdx.x;
  const int wid = tid >> 6, lane = tid & 63;
  const int wm = wid >> 1, wn = wid & 1;
  const long am0 = (long)blockIdx.x * 128;
  const long bn0 = (long)blockIdx.y * 128;

  f32x4 acc[4][4] = {};

  const int srow = wid * 32 + (lane >> 2);
  const int skoff = (lane & 3) * 8;
  const bf16_t* ag0 = A + (am0 + srow) * K + skoff;
  const bf16_t* ag1 = A + (am0 + srow + 16) * K + skoff;
  const bf16_t* bg0 = Bt + (bn0 + srow) * K + skoff;
  const bf16_t* bg1 = Bt + (bn0 + srow + 16) * K + skoff;
  bf16_t* al0 = As + (wid * 32) * 32;
  bf16_t* al1 = As + (wid * 32 + 16) * 32;
  bf16_t* bl0 = Bs + (wid * 32) * 32;
  bf16_t* bl1 = Bs + (wid * 32 + 16) * 32;

  const int fr = lane & 15;
  const int fk = (lane >> 4) * 8;
  const bf16_t* afrag = As + (wm * 64 + fr) * 32 + fk;
  const bf16_t* bfrag = Bs + (wn * 64 + fr) * 32 + fk;

  for (int k0 = 0; k0 < K; k0 += 32) {
    gld_lds16(ag0 + k0, al0);
    gld_lds16(ag1 + k0, al1);
    gld_lds16(bg0 + k0, bl0);
    gld_lds16(bg1 + k0, bl1);
    __syncthreads();
    bf16x8 a[4], b[4];
#pragma unroll
    for (int i = 0; i < 4; ++i) a[i] = *(const bf16x8*)(afrag + i * 16 * 32);
#pragma unroll
    for (int i = 0; i < 4; ++i) b[i] = *(const bf16x8*)(bfrag + i * 16 * 32);
#pragma unroll
    for (int mi = 0; mi < 4; ++mi)
#pragma unroll
      for (int ni = 0; ni < 4; ++ni)
        acc[mi][ni] = __builtin_amdgcn_mfma_f32_16x16x32_bf16(a[mi], b[ni], acc[mi][ni], 0, 0, 0);
    __syncthreads();
  }

  const int orow = wm * 64 + ((lane >> 4) << 2);
  const int ocol = wn * 64 + (lane & 15);
#pragma unroll
  for (int mi = 0; mi < 4; ++mi)
#pragma unroll
    for (int ni = 0; ni < 4; ++ni) {
      long col = bn0 + ocol + ni * 16;
#pragma unroll
      for (int r = 0; r < 4; ++r) {
        long row = am0 + orow + mi * 16 + r;
        float vv = acc[mi][ni][r];
        if (OUT_BF16) ((bf16_t*)Cout)[row * N + col] = (__bf16)vv;
        else          ((float*)Cout)[row * N + col] = vv + bias[col];
      }
    }
}

// ---------------------------------------------------------------- 256^2 8-phase GEMM (T2+T3+T4+T5)
// BM=BN=256, BK=64, 8 waves (2Mx4N), 128KB LDS double-buffer, swizzle cb^=(row&7)<<4.
// Stage units per K-tile: U_a=A blks 0,2; U_b=B nh0; U_c=B nh1; U_d=A blks 1,3.
// Issue stream 3 units ahead; single vmcnt(6) per tile at phase-3 before its mid-barrier.
template <bool OUT_BF16>
__global__ __launch_bounds__(512, 2) void gemm8p(const bf16_t* __restrict__ A,
                                                 const bf16_t* __restrict__ Bt,
                                                 void* __restrict__ Cout,
                                                 const float* __restrict__ bias,
                                                 int M, int N, int K) {
  __shared__ __align__(16) char lds[2][65536];  // per buf: A 32KB (4 blks of 64rx64k) | B 32KB
  const int tid = threadIdx.x, wid = tid >> 6, lane = tid & 63;
  const int wm = wid >> 2, wn = wid & 3;
  const int fr = lane & 15, fg = lane >> 4;
  const long am0 = (long)blockIdx.x * 256;
  const long bn0 = (long)blockIdx.y * 256;
  const long Kl = K;
  const int NTl = K >> 6;

  // ---- staging constants (linear LDS dest, inverse-swizzled global source)
  const int scol = (((lane & 7) ^ ((lane >> 3) & 7))) * 8;        // element offset in K
  const bf16_t* Ag = A + (am0 + wid * 8 + (lane >> 3)) * Kl + scol;
  const bf16_t* Bg = Bt + (bn0 + (wid >> 2) * 64 + (wid & 3) * 8 + (lane >> 3)) * Kl + scol;
  const int abst = wid * 1024 + lane * 16;
  const int bbst = 32768 + (wid >> 2) * 8192 + (wid & 3) * 1024 + lane * 16;

  // ---- frag read constants (byte offsets; swizzled)
  const int kx0 = (fg * 16) ^ ((fr & 7) << 4);
  const int kx1 = kx0 ^ 64;
  const int abase = wm * 16384 + fr * 128;
  const int bbase = 32768 + wn * 8192 + fr * 128;

  auto ISSUE = [&](int n) {
    if (n >= 4 * NTl) return;
    const int tile = n >> 2;
    char* l = lds[tile & 1];
    const long k0 = (long)(tile << 6);
    switch (n & 3) {
      case 0:  // U_a : A blks 0,2
        gld_lds16(Ag + k0, l + abst);
        gld_lds16(Ag + 128 * Kl + k0, l + 16384 + abst);
        break;
      case 1:  // U_b : B nh0 (rows 0-31 of each 64-blk)
        gld_lds16(Bg + k0, l + bbst);
        gld_lds16(Bg + 128 * Kl + k0, l + 16384 + bbst);
        break;
      case 2:  // U_c : B nh1 (rows 32-63 of each 64-blk)
        gld_lds16(Bg + 32 * Kl + k0, l + 4096 + bbst);
        gld_lds16(Bg + 160 * Kl + k0, l + 20480 + bbst);
        break;
      default: // U_d : A blks 1,3
        gld_lds16(Ag + 64 * Kl + k0, l + 8192 + abst);
        gld_lds16(Ag + 192 * Kl + k0, l + 24576 + abst);
    }
  };

  f32x4 acc[8][4] = {};
  bf16x8 a[4][2], b0[2][2], b1[2][2];

  // ---- prologue: tile0 complete + 3 units of tile1 in flight
  for (int n = 0; n < 7; ++n) ISSUE(n);
  asm volatile("s_waitcnt vmcnt(6)" ::: "memory");
  __builtin_amdgcn_s_barrier();

#pragma unroll 1
  for (int t = 0; t < NTl; ++t) {
    const char* l = lds[t & 1];
    const int base = t << 2;

    // ================ phase 0: (mh0, nh0) — read A-lo + B-lo
#pragma unroll
    for (int mi = 0; mi < 4; ++mi) {
      a[mi][0] = *(const bf16x8*)(l + abase + mi * 2048 + kx0);
      a[mi][1] = *(const bf16x8*)(l + abase + mi * 2048 + kx1);
    }
#pragma unroll
    for (int nj = 0; nj < 2; ++nj) {
      b0[nj][0] = *(const bf16x8*)(l + bbase + nj * 2048 + kx0);
      b0[nj][1] = *(const bf16x8*)(l + bbase + nj * 2048 + kx1);
    }
    ISSUE(base + 7);
    __builtin_amdgcn_s_barrier();
    asm volatile("s_waitcnt lgkmcnt(0)" ::: "memory");
    __builtin_amdgcn_sched_barrier(0);
    __builtin_amdgcn_s_setprio(1);
#pragma unroll
    for (int mi = 0; mi < 4; ++mi)
#pragma unroll
      for (int nj = 0; nj < 2; ++nj) {
        acc[mi][nj] = __builtin_amdgcn_mfma_f32_16x16x32_bf16(a[mi][0], b0[nj][0], acc[mi][nj], 0, 0, 0);
        acc[mi][nj] = __builtin_amdgcn_mfma_f32_16x16x32_bf16(a[mi][1], b0[nj][1], acc[mi][nj], 0, 0, 0);
      }
    __builtin_amdgcn_s_setprio(0);
    __builtin_amdgcn_s_barrier();

    // ================ phase 1: (mh0, nh1) — read B-hi, reuse A-lo
#pragma unroll
    for (int nj = 0; nj < 2; ++nj) {
      b1[nj][0] = *(const bf16x8*)(l + bbase + (2 + nj) * 2048 + kx0);
      b1[nj][1] = *(const bf16x8*)(l + bbase + (2 + nj) * 2048 + kx1);
    }
    ISSUE(base + 8);
    __builtin_amdgcn_s_barrier();
    asm volatile("s_waitcnt lgkmcnt(0)" ::: "memory");
    __builtin_amdgcn_sched_barrier(0);
    __builtin_amdgcn_s_setprio(1);
#pragma unroll
    for (int mi = 0; mi < 4; ++mi)
#pragma unroll
      for (int nj = 0; nj < 2; ++nj) {
        acc[mi][2 + nj] = __builtin_amdgcn_mfma_f32_16x16x32_bf16(a[mi][0], b1[nj][0], acc[mi][2 + nj], 0, 0, 0);
        acc[mi][2 + nj] = __builtin_amdgcn_mfma_f32_16x16x32_bf16(a[mi][1], b1[nj][1], acc[mi][2 + nj], 0, 0, 0);
      }
    __builtin_amdgcn_s_setprio(0);
    __builtin_amdgcn_s_barrier();

    // ================ phase 2: (mh1, nh1) — read A-hi (overwrite a[]), reuse B-hi
#pragma unroll
    for (int mi = 0; mi < 4; ++mi) {
      a[mi][0] = *(const bf16x8*)(l + abase + 8192 + mi * 2048 + kx0);
      a[mi][1] = *(const bf16x8*)(l + abase + 8192 + mi * 2048 + kx1);
    }
    ISSUE(base + 9);
    __builtin_amdgcn_s_barrier();
    asm volatile("s_waitcnt lgkmcnt(0)" ::: "memory");
    __builtin_amdgcn_sched_barrier(0);
    __builtin_amdgcn_s_setprio(1);
#pragma unroll
    for (int mi = 0; mi < 4; ++mi)
#pragma unroll
      for (int nj = 0; nj < 2; ++nj) {
        acc[4 + mi][2 + nj] = __builtin_amdgcn_mfma_f32_16x16x32_bf16(a[mi][0], b1[nj][0], acc[4 + mi][2 + nj], 0, 0, 0);
        acc[4 + mi][2 + nj] = __builtin_amdgcn_mfma_f32_16x16x32_bf16(a[mi][1], b1[nj][1], acc[4 + mi][2 + nj], 0, 0, 0);
      }
    __builtin_amdgcn_s_setprio(0);
    __builtin_amdgcn_s_barrier();

    // ================ phase 3: (mh1, nh0) — no reads; boundary vmcnt BEFORE mid-barrier
    ISSUE(base + 10);
    if (t < NTl - 2)      asm volatile("s_waitcnt vmcnt(6)" ::: "memory");
    else                  asm volatile("s_waitcnt vmcnt(0)" ::: "memory");
    __builtin_amdgcn_s_barrier();
    asm volatile("s_waitcnt lgkmcnt(0)" ::: "memory");
    __builtin_amdgcn_sched_barrier(0);
    __builtin_amdgcn_s_setprio(1);
#pragma unroll
    for (int mi = 0; mi < 4; ++mi)
#pragma unroll
      for (int nj = 0; nj < 2; ++nj) {
        acc[4 + mi][nj] = __builtin_amdgcn_mfma_f32_16x16x32_bf16(a[mi][0], b0[nj][0], acc[4 + mi][nj], 0, 0, 0);
        acc[4 + mi][nj] = __builtin_amdgcn_mfma_f32_16x16x32_bf16(a[mi][1], b0[nj][1], acc[4 + mi][nj], 0, 0, 0);
      }
    __builtin_amdgcn_s_setprio(0);
    __builtin_amdgcn_s_barrier();
  }

  // ---- epilogue
#pragma unroll
  for (int mi = 0; mi < 8; ++mi)
#pragma unroll
    for (int nj = 0; nj < 4; ++nj) {
      long col = bn0 + wn * 64 + nj * 16 + fr;
#pragma unroll
      for (int r = 0; r < 4; ++r) {
        long row = am0 + wm * 128 + mi * 16 + fg * 4 + r;
        float vv = acc[mi][nj][r];
        if (OUT_BF16) ((bf16_t*)Cout)[row * N + col] = (__bf16)vv;
        else          ((float*)Cout)[row * N + col] = vv + bias[col];
      }
    }
}

// ---------------------------------------------------------------- flash attention (unchanged from R2)
__global__ __launch_bounds__(256) void attn_fwd(const bf16_t* __restrict__ qkv,
                                                const bf16_t* __restrict__ vt,
                                                bf16_t* __restrict__ y) {
  __shared__ __align__(16) bf16_t Kt[2][64 * 128];
  __shared__ __align__(16) bf16_t Vt[2][128 * 64];
  __shared__ __align__(16) bf16_t Pb[4][32 * 64];

  const int tid = threadIdx.x, wid = tid >> 6, lane = tid & 63;
  const int fr = lane & 15, fg = lane >> 4;
  const int bh = blockIdx.y;
  const int b = bh >> 4, h = bh & 15, kvh = h >> 2;
  const int bx = blockIdx.x;
  const long rowbase = (long)b * NT;
  char* PbB = (char*)Pb[wid];

  const bf16_t* ksrc[4];
  const bf16_t* vsrc[4];
#pragma unroll
  for (int i = 0; i < 4; ++i) {
    int kvl = wid * 16 + i * 4 + fg;
    int dbyte = ((lane & 15) * 16) ^ ((kvl & 7) << 4);
    ksrc[i] = qkv + (rowbase + kvl) * (long)LDQ + NC + kvh * ND + (dbyte >> 1);
    int d = wid * 32 + i * 8 + (lane >> 3);
    int kvbyte = ((lane & 7) * 16) ^ ((d & 7) << 4);
    vsrc[i] = vt + (long)(kvh * ND + d) * (NB * NT) + rowbase + (kvbyte >> 1);
  }

  auto STAGE = [&](int buf, int kv0) {
#pragma unroll
    for (int i = 0; i < 4; ++i)
      gld_lds16(ksrc[i] + (long)kv0 * LDQ, &Kt[buf][(wid * 16 + i * 4) * 128]);
#pragma unroll
    for (int i = 0; i < 4; ++i)
      gld_lds16(vsrc[i] + kv0, &Vt[buf][(wid * 32 + i * 8) * 64]);
  };

  int cur = 0;
#pragma unroll 1
  for (int phase = 0; phase < 2; ++phase) {
    const int qt = phase ? (15 - bx) : bx;
    const int q0 = qt * 128;
    const int ntiles = 2 * qt + 2;

    bf16x8 qf[2][4];
#pragma unroll
    for (int mi = 0; mi < 2; ++mi) {
      const bf16_t* qp = qkv + (rowbase + q0 + wid * 32 + mi * 16 + fr) * (long)LDQ + h * ND + fg * 8;
#pragma unroll
      for (int ks = 0; ks < 4; ++ks) qf[mi][ks] = *(const bf16x8*)(qp + ks * 32);
    }

    f32x4 o[2][8] = {};
    float m_st[2][4], l_st[2][4];
#pragma unroll
    for (int mi = 0; mi < 2; ++mi)
#pragma unroll
      for (int r = 0; r < 4; ++r) { m_st[mi][r] = -3e38f; l_st[mi][r] = 0.f; }

    STAGE(cur, 0);
    __syncthreads();

#pragma unroll 1
    for (int t = 0; t < ntiles; ++t) {
      const int kv0 = t * 64;
      if (t + 1 < ntiles) STAGE(cur ^ 1, kv0 + 64);

      const char* KtB = (const char*)Kt[cur];
      const char* VtB = (const char*)Vt[cur];

      f32x4 s[2][4] = {};
#pragma unroll
      for (int ks = 0; ks < 4; ++ks)
#pragma unroll
        for (int ni = 0; ni < 4; ++ni) {
          bf16x8 kb = *(const bf16x8*)(KtB + (ni * 16 + fr) * 256 +
                                       ((ks * 64 + fg * 16) ^ ((fr & 7) << 4)));
          s[0][ni] = __builtin_amdgcn_mfma_f32_16x16x32_bf16(qf[0][ks], kb, s[0][ni], 0, 0, 0);
          s[1][ni] = __builtin_amdgcn_mfma_f32_16x16x32_bf16(qf[1][ks], kb, s[1][ni], 0, 0, 0);
        }

      if (t >= 2 * qt) {
#pragma unroll
        for (int mi = 0; mi < 2; ++mi)
#pragma unroll
          for (int ni = 0; ni < 4; ++ni) {
            int j = kv0 + ni * 16 + fr;
#pragma unroll
            for (int r = 0; r < 4; ++r) {
              int i_ = q0 + wid * 32 + mi * 16 + fg * 4 + r;
              if (j > i_) s[mi][ni][r] = -3e30f;
            }
          }
      }

      float alpha[2][4];
#pragma unroll
      for (int mi = 0; mi < 2; ++mi)
#pragma unroll
        for (int r = 0; r < 4; ++r) {
          float rm = fmaxf(fmaxf(s[mi][0][r], s[mi][1][r]), fmaxf(s[mi][2][r], s[mi][3][r]));
          rm = fmaxf(rm, __shfl_xor(rm, 1));
          rm = fmaxf(rm, __shfl_xor(rm, 2));
          rm = fmaxf(rm, __shfl_xor(rm, 4));
          rm = fmaxf(rm, __shfl_xor(rm, 8));
          float mn = fmaxf(m_st[mi][r], rm);
          alpha[mi][r] = __expf(m_st[mi][r] - mn);
          m_st[mi][r] = mn;
        }
#pragma unroll
      for (int mi = 0; mi < 2; ++mi)
#pragma unroll
        for (int ni = 0; ni < 4; ++ni)
#pragma unroll
          for (int r = 0; r < 4; ++r)
            s[mi][ni][r] = __expf(s[mi][ni][r] - m_st[mi][r]);
#pragma unroll
      for (int mi = 0; mi < 2; ++mi)
#pragma unroll
        for (int r = 0; r < 4; ++r) {
          float t2 = s[mi][0][r] + s[mi][1][r] + s[mi][2][r] + s[mi][3][r];
          t2 += __shfl_xor(t2, 1);
          t2 += __shfl_xor(t2, 2);
          t2 += __shfl_xor(t2, 4);
          t2 += __shfl_xor(t2, 8);
          l_st[mi][r] = l_st[mi][r] * alpha[mi][r] + t2;
        }
#pragma unroll
      for (int mi = 0; mi < 2; ++mi)
#pragma unroll
        for (int n = 0; n < 8; ++n)
#pragma unroll
          for (int r = 0; r < 4; ++r) o[mi][n][r] *= alpha[mi][r];

#pragma unroll
      for (int mi = 0; mi < 2; ++mi)
#pragma unroll
        for (int ni = 0; ni < 4; ++ni)
#pragma unroll
          for (int r = 0; r < 4; ++r) {
            int m = mi * 16 + fg * 4 + r;
            int byte = m * 128 + ((ni * 32 + fr * 2) ^ ((m & 7) << 4));
            *(bf16_t*)(PbB + byte) = (__bf16)s[mi][ni][r];
          }
      bf16x8 pa[2][2];
#pragma unroll
      for (int mi = 0; mi < 2; ++mi)
#pragma unroll
        for (int ks = 0; ks < 2; ++ks) {
          int m = mi * 16 + fr;
          pa[mi][ks] = *(const bf16x8*)(PbB + m * 128 + ((ks * 64 + fg * 16) ^ ((m & 7) << 4)));
        }
#pragma unroll
      for (int ks = 0; ks < 2; ++ks)
#pragma unroll
        for (int n = 0; n < 8; ++n) {
          bf16x8 vb = *(const bf16x8*)(VtB + (n * 16 + fr) * 128 +
                                       ((ks * 64 + fg * 16) ^ ((fr & 7) << 4)));
          o[0][n] = __builtin_amdgcn_mfma_f32_16x16x32_bf16(pa[0][ks], vb, o[0][n], 0, 0, 0);
          o[1][n] = __builtin_amdgcn_mfma_f32_16x16x32_bf16(pa[1][ks], vb, o[1][n], 0, 0, 0);
        }
      __syncthreads();
      cur ^= 1;
    }

#pragma unroll
    for (int mi = 0; mi < 2; ++mi)
#pragma unroll
      for (int r = 0; r < 4; ++r) {
        float rinv = 1.0f / l_st[mi][r];
        long row = rowbase + q0 + wid * 32 + mi * 16 + fg * 4 + r;
#pragma unroll
        for (int n = 0; n < 8; ++n)
          y[row * NC + h * ND + n * 16 + fr] = (__bf16)(o[mi][n][r] * rinv);
      }
  }
}

// ---------------------------------------------------------------- launch
extern "C" void kernel_launch(void* const* d_in, const int* in_sizes, int n_in,
                              void* d_out, int out_size, void* d_ws, size_t ws_size,
                              hipStream_t stream) {
  const float* x  = (const float*)d_in[0];
  const float* iv = (const float*)d_in[2];
  const float* Wq = (const float*)d_in[4];
  const float* Wk = (const float*)d_in[5];
  const float* Wv = (const float*)d_in[6];
  const float* Wo = (const float*)d_in[7];
  const float* bo = (const float*)d_in[8];
  float* out = (float*)d_out;

  char* ws = (char*)d_ws;
  size_t off = 0;
  auto alloc = [&](size_t bytes) -> void* {
    void* p = ws + off;
    off += (bytes + 255) & ~(size_t)255;
    return p;
  };
  bf16_t* xb   = (bf16_t*)alloc((size_t)NB * NT * NC * 2);
  bf16_t* Wcat = (bf16_t*)alloc((size_t)2560 * 2048 * 2);
  bf16_t* Wvb  = (bf16_t*)alloc((size_t)512 * 2048 * 2);
  bf16_t* Wob  = (bf16_t*)alloc((size_t)2048 * 2048 * 2);
  bf16_t* qkv  = (bf16_t*)alloc((size_t)NB * NT * LDQ * 2);
  bf16_t* vtb  = (bf16_t*)alloc((size_t)512 * NB * NT * 2);
  bf16_t* yb   = (bf16_t*)alloc((size_t)NB * NT * NC * 2);
  float*  ctab = (float*)alloc((size_t)NT * 64 * 4);
  float*  stab = (float*)alloc((size_t)NT * 64 * 4);

  cast_f32_bf16<<<16384, 256, 0, stream>>>(x, xb, 4194304);
  cast_f32_bf16<<<4096, 256, 0, stream>>>(Wq, Wcat, 1048576);
  cast_f32_bf16<<<1024, 256, 0, stream>>>(Wk, Wcat + (size_t)2048 * 2048, 262144);
  cast_f32_bf16<<<1024, 256, 0, stream>>>(Wv, Wvb, 262144);
  cast_f32_bf16<<<4096, 256, 0, stream>>>(Wo, Wob, 1048576);
  rope_table<<<512, 256, 0, stream>>>(iv, ctab, stab);

  // fused Q|K projection: [8192,2048] x [2560,2048]^T -> qkv (8-phase 256^2)
  gemm8p<true><<<dim3(32, 10), 512, 0, stream>>>(xb, Wcat, qkv, nullptr, 8192, 2560, 2048);
  // V^T projection: [512,2048] x [8192,2048]^T -> vtb[d][b*t] (128^2 kernel; skinny M)
  gemm_bt<true><<<dim3(4, 64), 256, 0, stream>>>(Wvb, xb, vtb, nullptr, 512, 8192, 2048);

  rope_apply<<<8192, 256, 0, stream>>>(qkv, ctab, stab, 0, NH, 0.08838834764831843f);
  rope_apply<<<2048, 256, 0, stream>>>(qkv, ctab, stab, NC, NKVH, 1.0f);

  attn_fwd<<<dim3(8, 64), 256, 0, stream>>>(qkv, vtb, yb);

  // output projection + bias -> fp32 out (8-phase 256^2)
  gemm8p<false><<<dim3(32, 8), 512, 0, stream>>>(yb, Wob, out, bo, 8192, 2048, 2048);
}